// Round 14
// baseline (99.216 us; speedup 1.0000x reference)
//
#include <hip/hip_runtime.h>
#include <math.h>
#include <type_traits>

// SDE Euler-Maruyama path generator — affine-scan decomposition, v13b.
//   step:  x' = S_k x + t_k,  S_k = I + dt*A + diag(dW_k)*C,  t_k = dt*b + dW_k*d
// v13 with the off-by-one store-bound fix (jhi2 includes state t=2500).
// Replay: NO LDS — each lane streams its own phi-aligned 768B region
// [64c+phi, 64c+64+phi) with plain dwordx3 stores (per-lane sequential ->
// L2 write-combines, lines complete in <=6 stores); ~16 waves/CU.

constexpr int B_N  = 4096;
constexpr int T_N  = 2500;
constexpr int CL   = 64;            // steps per chunk
constexpr int NFC  = T_N / CL;      // 39 full chunks (2496 steps)
constexpr int NCH  = NFC + 1;       // 40 (incl. tail wave)
constexpr int FLP  = 8;             // noise prefetch sub-chunk
constexpr int ROWF = (T_N + 1) * 3; // floats per output path row

template <int N> using ic = std::integral_constant<int, N>;
typedef float f4v __attribute__((ext_vector_type(4)));

// d_ws (floats): trans [NCH][B][12] — slots 0..38 hold (M 9, v 3); scan
// overwrites slot c's first float4 with boundary state x_{64c}, c=0..39.

__global__ __launch_bounds__(64)
void sde_chunk_transforms(const float* __restrict__ A,
                          const float* __restrict__ bv,
                          const float* __restrict__ C,
                          const float* __restrict__ dv,
                          const float* __restrict__ noise,
                          float* __restrict__ trans)
{
    const int b = blockIdx.x * 64 + threadIdx.x;
    const int c = blockIdx.y;          // 0..38

    const float dt  = 0.002f;
    const float sdt = sqrtf(dt);

    float IA[3][3], Cs[3][3], bdt[3], ds[3];
#pragma unroll
    for (int i = 0; i < 3; ++i) {
        bdt[i] = bv[i] * dt;
        ds[i]  = dv[i] * sdt;
#pragma unroll
        for (int j = 0; j < 3; ++j) {
            IA[i][j] = A[i * 3 + j] * dt + (i == j ? 1.0f : 0.0f);
            Cs[i][j] = C[i * 3 + j] * sdt;
        }
    }

    float M[3][3] = {{1,0,0},{0,1,0},{0,0,1}};
    float v[3] = {0, 0, 0};

    const float* __restrict__ nb = noise + (size_t)c * CL * (B_N * 3) + (size_t)b * 3;
    const size_t nstride = (size_t)B_N * 3;

    float bufA[FLP][3], bufB[FLP][3];

    auto loadChunk = [&](float (&buf)[FLP][3], int s) {
#pragma unroll
        for (int k = 0; k < FLP; ++k) {
            const float* p = nb + ((size_t)s * FLP + k) * nstride;
            buf[k][0] = p[0];
            buf[k][1] = p[1];
            buf[k][2] = p[2];
        }
    };

    auto compChunk = [&](const float (&buf)[FLP][3]) {
#pragma unroll
        for (int k = 0; k < FLP; ++k) {
            const float e[3] = { buf[k][0], buf[k][1], buf[k][2] };
            float S[3][3], t[3];
#pragma unroll
            for (int i = 0; i < 3; ++i) {
                t[i] = fmaf(e[i], ds[i], bdt[i]);
#pragma unroll
                for (int j = 0; j < 3; ++j)
                    S[i][j] = fmaf(e[i], Cs[i][j], IA[i][j]);
            }
            float nM[3][3], nv[3];
#pragma unroll
            for (int i = 0; i < 3; ++i) {
#pragma unroll
                for (int j = 0; j < 3; ++j)
                    nM[i][j] = fmaf(S[i][2], M[2][j], fmaf(S[i][1], M[1][j], S[i][0] * M[0][j]));
                nv[i] = fmaf(S[i][2], v[2], fmaf(S[i][1], v[1], S[i][0] * v[0])) + t[i];
            }
#pragma unroll
            for (int i = 0; i < 3; ++i) {
                v[i] = nv[i];
#pragma unroll
                for (int j = 0; j < 3; ++j) M[i][j] = nM[i][j];
            }
        }
    };

    // CL/FLP = 8 sub-chunks, double-buffered
    loadChunk(bufA, 0);
    loadChunk(bufB, 1);
    compChunk(bufA); loadChunk(bufA, 2);
    compChunk(bufB); loadChunk(bufB, 3);
    compChunk(bufA); loadChunk(bufA, 4);
    compChunk(bufB); loadChunk(bufB, 5);
    compChunk(bufA); loadChunk(bufA, 6);
    compChunk(bufB); loadChunk(bufB, 7);
    compChunk(bufA);
    compChunk(bufB);

    float* tp = trans + ((size_t)c * B_N + b) * 12;
    float4 w0 = { M[0][0], M[0][1], M[0][2], M[1][0] };
    float4 w1 = { M[1][1], M[1][2], M[2][0], M[2][1] };
    float4 w2 = { M[2][2], v[0],    v[1],    v[2]    };
    ((float4*)tp)[0] = w0;
    ((float4*)tp)[1] = w1;
    ((float4*)tp)[2] = w2;
}

__global__ __launch_bounds__(64)
void sde_scan(const float* __restrict__ x0,
              float* __restrict__ trans)
{
    const int b = blockIdx.x * 64 + threadIdx.x;

    float x[3] = { x0[b * 3 + 0], x0[b * 3 + 1], x0[b * 3 + 2] };

    float4* tp0 = (float4*)(trans + (size_t)b * 12);
    const size_t cs = (size_t)B_N * 3;   // float4 stride between chunk slots

    float4 qa0, qa1, qa2, qb0, qb1, qb2, qc0, qc1, qc2, qd0, qd1, qd2;

    auto L = [&](int s, float4& r0, float4& r1, float4& r2) {
        const float4* tn = tp0 + (size_t)s * cs;
        r0 = tn[0]; r1 = tn[1]; r2 = tn[2];
    };
    auto useSlot = [&](int s, const float4& a0, const float4& a1, const float4& a2) {
        // overwrite slot (already consumed) with boundary state x_{64s}
        tp0[(size_t)s * cs] = make_float4(x[0], x[1], x[2], 0.0f);
        const float n0 = fmaf(a0.x, x[0], fmaf(a0.y, x[1], fmaf(a0.z, x[2], a2.y)));
        const float n1 = fmaf(a0.w, x[0], fmaf(a1.x, x[1], fmaf(a1.y, x[2], a2.z)));
        const float n2 = fmaf(a1.z, x[0], fmaf(a1.w, x[1], fmaf(a2.x, x[2], a2.w)));
        x[0] = n0; x[1] = n1; x[2] = n2;
    };

    L(0, qa0, qa1, qa2);
    L(1, qb0, qb1, qb2);
    L(2, qc0, qc1, qc2);
    L(3, qd0, qd1, qd2);

    for (int it = 0; it < 9; ++it) {     // slots 0..35, depth-4 prefetch
        const int s = it * 4;
        useSlot(s + 0, qa0, qa1, qa2);
        if (s + 4 < NFC) L(s + 4, qa0, qa1, qa2);
        useSlot(s + 1, qb0, qb1, qb2);
        if (s + 5 < NFC) L(s + 5, qb0, qb1, qb2);
        useSlot(s + 2, qc0, qc1, qc2);
        if (s + 6 < NFC) L(s + 6, qc0, qc1, qc2);
        useSlot(s + 3, qd0, qd1, qd2);
        if (s + 7 < NFC) L(s + 7, qd0, qd1, qd2);
    }
    useSlot(36, qa0, qa1, qa2);          // remainder 36,37,38
    useSlot(37, qb0, qb1, qb2);
    useSlot(38, qc0, qc1, qc2);

    // boundary for the tail wave: x_{2496}
    tp0[(size_t)NFC * cs] = make_float4(x[0], x[1], x[2], 0.0f);
}

__global__ __launch_bounds__(64)
void sde_replay(const float* __restrict__ A,
                const float* __restrict__ bv,
                const float* __restrict__ C,
                const float* __restrict__ dv,
                const float* __restrict__ noise,
                const float* __restrict__ trans,
                float* __restrict__ out)
{
    const int lane = threadIdx.x & 63;
    const int pg   = blockIdx.x & 63;   // path group
    const int c    = blockIdx.x >> 6;   // chunk 0..39
    const int b    = (pg << 6) | lane;
    const int phi  = (11 * lane) & 15;  // own path's alignment phase

    const float dt  = 0.002f;
    const float sdt = sqrtf(dt);

    float Adt[3][3], Cs[3][3], bdt[3], dsv[3];
#pragma unroll
    for (int i = 0; i < 3; ++i) {
        bdt[i] = bv[i] * dt;
        dsv[i] = dv[i] * sdt;
#pragma unroll
        for (int j = 0; j < 3; ++j) {
            Adt[i][j] = A[i * 3 + j] * dt;
            Cs[i][j]  = C[i * 3 + j] * sdt;
        }
    }

    const f4v xb = __builtin_nontemporal_load(
        (const f4v*)(trans + ((size_t)c * B_N + b) * 12));
    float x0r = xb.x, x1r = xb.y, x2r = xb.z;

    const float* __restrict__ nb0 = noise + (size_t)b * 3;
    const size_t nstride = (size_t)B_N * 3;
    const int base = c * CL;

    auto stepf = [&](float e0, float e1, float e2) {
        const float a0 = fmaf(Adt[0][2], x2r, fmaf(Adt[0][1], x1r, fmaf(Adt[0][0], x0r, bdt[0])));
        const float a1 = fmaf(Adt[1][2], x2r, fmaf(Adt[1][1], x1r, fmaf(Adt[1][0], x0r, bdt[1])));
        const float a2 = fmaf(Adt[2][2], x2r, fmaf(Adt[2][1], x1r, fmaf(Adt[2][0], x0r, bdt[2])));

        const float c0 = fmaf(Cs[0][2], x2r, fmaf(Cs[0][1], x1r, fmaf(Cs[0][0], x0r, dsv[0])));
        const float c1 = fmaf(Cs[1][2], x2r, fmaf(Cs[1][1], x1r, fmaf(Cs[1][0], x0r, dsv[1])));
        const float c2 = fmaf(Cs[2][2], x2r, fmaf(Cs[2][1], x1r, fmaf(Cs[2][0], x0r, dsv[2])));

        x0r = fmaf(c0, e0, x0r + a0);
        x1r = fmaf(c1, e1, x1r + a1);
        x2r = fmaf(c2, e2, x2r + a2);
    };

    if (c == NFC) {
        // tail wave: path p writes states [2496+phi, 2501) (only phi<=4 has any)
        float* op = out + (size_t)b * ROWF;
        if (phi == 0) {
            op[2496 * 3 + 0] = x0r; op[2496 * 3 + 1] = x1r; op[2496 * 3 + 2] = x2r;
        }
#pragma unroll
        for (int k = 0; k < 4; ++k) {
            const float* p = nb0 + (size_t)(2496 + k) * nstride;
            stepf(p[0], p[1], p[2]);
            const int j = k + 1;
            if (j >= phi) {
                float* d = op + (size_t)(2496 + j) * 3;
                d[0] = x0r; d[1] = x1r; d[2] = x2r;
            }
        }
        return;
    }

    const bool c0   = (c == 0);
    const bool last = (c == NFC - 1);
    const int  jlo  = c0 ? 0 : phi;                  // first stored local state
    const int  jhi1 = phi + 64;                      // one past last (phase window)
    const int  jhi2 = last ? (T_N + 1 - base) : 127; // state t <= 2500 (FIX: +1)
    const int  jhi  = jhi1 < jhi2 ? jhi1 : jhi2;

    // own path's streaming store pointer (indexed by local state j)
    float* const op = out + (size_t)b * ROWF + (size_t)base * 3;

    // j = 0 (boundary state)
    if (jlo == 0) { op[0] = x0r; op[1] = x1r; op[2] = x2r; }

    float bufA[FLP][3], bufB[FLP][3];

    auto loadN = [&](float (&buf)[FLP][3], int kbase) {
#pragma unroll
        for (int k = 0; k < FLP; ++k) {
            int g = base + kbase + k;
            g = g > (T_N - 1) ? (T_N - 1) : g;   // clamp overrun (stores masked)
            const float* p = nb0 + (size_t)g * nstride;
            buf[k][0] = p[0];
            buf[k][1] = p[1];
            buf[k][2] = p[2];
        }
    };

    auto compGroup = [&](const float (&buf)[FLP][3], int jbase) {
#pragma unroll
        for (int k = 0; k < FLP; ++k) {
            stepf(buf[k][0], buf[k][1], buf[k][2]);
            const int j = jbase + k + 1;
            if (j >= jlo && j < jhi) {
                float* d = op + (size_t)j * 3;
                d[0] = x0r; d[1] = x1r; d[2] = x2r;
            }
        }
    };

    // 10 groups of 8 steps (j = 1..80; stores masked to [jlo, jhi))
    loadN(bufA, 0);
    loadN(bufB, 8);
    compGroup(bufA, 0);  loadN(bufA, 16);
    compGroup(bufB, 8);  loadN(bufB, 24);
    compGroup(bufA, 16); loadN(bufA, 32);
    compGroup(bufB, 24); loadN(bufB, 40);
    compGroup(bufA, 32); loadN(bufA, 48);
    compGroup(bufB, 40); loadN(bufB, 56);
    compGroup(bufA, 48); loadN(bufA, 64);
    compGroup(bufB, 56); loadN(bufB, 72);
    compGroup(bufA, 64);
    compGroup(bufB, 72);
}

extern "C" void kernel_launch(void* const* d_in, const int* in_sizes, int n_in,
                              void* d_out, int out_size, void* d_ws, size_t ws_size,
                              hipStream_t stream) {
    const float* x0    = (const float*)d_in[0];
    const float* A     = (const float*)d_in[1];
    const float* bv    = (const float*)d_in[2];
    const float* C     = (const float*)d_in[3];
    const float* dv    = (const float*)d_in[4];
    const float* noise = (const float*)d_in[5];
    float* out = (float*)d_out;

    float* trans = (float*)d_ws;   // 7.86 MB

    dim3 gridPC(B_N / 64, NFC);

    sde_chunk_transforms<<<gridPC, 64, 0, stream>>>(A, bv, C, dv, noise, trans);
    sde_scan<<<B_N / 64, 64, 0, stream>>>(x0, trans);
    sde_replay<<<64 * NCH, 64, 0, stream>>>(A, bv, C, dv, noise, trans, out);
}

// Round 15
// 80.728 us; speedup vs baseline: 1.2290x; 1.2290x over previous
//
#include <hip/hip_runtime.h>
#include <math.h>
#include <type_traits>

// SDE Euler-Maruyama path generator — affine-scan decomposition, v12 (FINAL).
//   step:  x' = S_k x + t_k,  S_k = I + dt*A + diag(dW_k)*C,  t_k = dt*b + dW_k*d
// Measured optimum (r12: 80.9 us total; WRITE == ideal 122 MB, 0 bank conflicts):
//   - phi-phase aligned full-line nt stores (phi_p = (11p)&15 makes every
//     192B/16-state segment 3 whole aligned 64B lines for EVERY path)
//   - rolling-32-state LDS transpose window, conflict-free [96][66] tile
//   - CL=64 chunks, reversed chunk dispatch (MALL LRU-friendly)

constexpr int B_N  = 4096;
constexpr int T_N  = 2500;
constexpr int CL   = 64;            // steps per chunk (64c == 0 mod 16: phase math holds)
constexpr int NFC  = T_N / CL;      // 39 full chunks (2496 steps)
constexpr int NCH  = NFC + 1;       // 40 (incl. tail wave)
constexpr int FLP  = 8;             // phase-1 noise prefetch sub-chunk
constexpr int ROWF = (T_N + 1) * 3; // floats per output path row

template <int N> using ic = std::integral_constant<int, N>;
typedef float f4v __attribute__((ext_vector_type(4)));

// d_ws (floats): trans [NCH][B][12] — slots 0..38 hold (M 9, v 3); scan
// overwrites slot c's first float4 with boundary state x_{64c}, c=0..39.

__global__ __launch_bounds__(64)
void sde_chunk_transforms(const float* __restrict__ A,
                          const float* __restrict__ bv,
                          const float* __restrict__ C,
                          const float* __restrict__ dv,
                          const float* __restrict__ noise,
                          float* __restrict__ trans)
{
    const int b = blockIdx.x * 64 + threadIdx.x;
    const int c = blockIdx.y;          // 0..38

    const float dt  = 0.002f;
    const float sdt = sqrtf(dt);

    float IA[3][3], Cs[3][3], bdt[3], ds[3];
#pragma unroll
    for (int i = 0; i < 3; ++i) {
        bdt[i] = bv[i] * dt;
        ds[i]  = dv[i] * sdt;
#pragma unroll
        for (int j = 0; j < 3; ++j) {
            IA[i][j] = A[i * 3 + j] * dt + (i == j ? 1.0f : 0.0f);
            Cs[i][j] = C[i * 3 + j] * sdt;
        }
    }

    float M[3][3] = {{1,0,0},{0,1,0},{0,0,1}};
    float v[3] = {0, 0, 0};

    const float* __restrict__ nb = noise + (size_t)c * CL * (B_N * 3) + (size_t)b * 3;
    const size_t nstride = (size_t)B_N * 3;

    float bufA[FLP][3], bufB[FLP][3];

    auto loadChunk = [&](float (&buf)[FLP][3], int s) {
#pragma unroll
        for (int k = 0; k < FLP; ++k) {
            const float* p = nb + ((size_t)s * FLP + k) * nstride;
            buf[k][0] = p[0];
            buf[k][1] = p[1];
            buf[k][2] = p[2];
        }
    };

    auto compChunk = [&](const float (&buf)[FLP][3]) {
#pragma unroll
        for (int k = 0; k < FLP; ++k) {
            const float e[3] = { buf[k][0], buf[k][1], buf[k][2] };
            float S[3][3], t[3];
#pragma unroll
            for (int i = 0; i < 3; ++i) {
                t[i] = fmaf(e[i], ds[i], bdt[i]);
#pragma unroll
                for (int j = 0; j < 3; ++j)
                    S[i][j] = fmaf(e[i], Cs[i][j], IA[i][j]);
            }
            float nM[3][3], nv[3];
#pragma unroll
            for (int i = 0; i < 3; ++i) {
#pragma unroll
                for (int j = 0; j < 3; ++j)
                    nM[i][j] = fmaf(S[i][2], M[2][j], fmaf(S[i][1], M[1][j], S[i][0] * M[0][j]));
                nv[i] = fmaf(S[i][2], v[2], fmaf(S[i][1], v[1], S[i][0] * v[0])) + t[i];
            }
#pragma unroll
            for (int i = 0; i < 3; ++i) {
                v[i] = nv[i];
#pragma unroll
                for (int j = 0; j < 3; ++j) M[i][j] = nM[i][j];
            }
        }
    };

    // CL/FLP = 8 sub-chunks, double-buffered
    loadChunk(bufA, 0);
    loadChunk(bufB, 1);
    compChunk(bufA); loadChunk(bufA, 2);
    compChunk(bufB); loadChunk(bufB, 3);
    compChunk(bufA); loadChunk(bufA, 4);
    compChunk(bufB); loadChunk(bufB, 5);
    compChunk(bufA); loadChunk(bufA, 6);
    compChunk(bufB); loadChunk(bufB, 7);
    compChunk(bufA);
    compChunk(bufB);

    float* tp = trans + ((size_t)c * B_N + b) * 12;
    float4 w0 = { M[0][0], M[0][1], M[0][2], M[1][0] };
    float4 w1 = { M[1][1], M[1][2], M[2][0], M[2][1] };
    float4 w2 = { M[2][2], v[0],    v[1],    v[2]    };
    ((float4*)tp)[0] = w0;
    ((float4*)tp)[1] = w1;
    ((float4*)tp)[2] = w2;
}

__global__ __launch_bounds__(64)
void sde_scan(const float* __restrict__ x0,
              float* __restrict__ trans)
{
    const int b = blockIdx.x * 64 + threadIdx.x;

    float x[3] = { x0[b * 3 + 0], x0[b * 3 + 1], x0[b * 3 + 2] };

    float4* tp0 = (float4*)(trans + (size_t)b * 12);
    const size_t cs = (size_t)B_N * 3;   // float4 stride between chunk slots

    float4 qa0, qa1, qa2, qb0, qb1, qb2, qc0, qc1, qc2, qd0, qd1, qd2;

    auto L = [&](int s, float4& r0, float4& r1, float4& r2) {
        const float4* tn = tp0 + (size_t)s * cs;
        r0 = tn[0]; r1 = tn[1]; r2 = tn[2];
    };
    auto useSlot = [&](int s, const float4& a0, const float4& a1, const float4& a2) {
        // overwrite slot (already consumed) with boundary state x_{64s}
        tp0[(size_t)s * cs] = make_float4(x[0], x[1], x[2], 0.0f);
        const float n0 = fmaf(a0.x, x[0], fmaf(a0.y, x[1], fmaf(a0.z, x[2], a2.y)));
        const float n1 = fmaf(a0.w, x[0], fmaf(a1.x, x[1], fmaf(a1.y, x[2], a2.z)));
        const float n2 = fmaf(a1.z, x[0], fmaf(a1.w, x[1], fmaf(a2.x, x[2], a2.w)));
        x[0] = n0; x[1] = n1; x[2] = n2;
    };

    L(0, qa0, qa1, qa2);
    L(1, qb0, qb1, qb2);
    L(2, qc0, qc1, qc2);
    L(3, qd0, qd1, qd2);

    for (int it = 0; it < 9; ++it) {     // slots 0..35, depth-4 prefetch
        const int s = it * 4;
        useSlot(s + 0, qa0, qa1, qa2);
        if (s + 4 < NFC) L(s + 4, qa0, qa1, qa2);
        useSlot(s + 1, qb0, qb1, qb2);
        if (s + 5 < NFC) L(s + 5, qb0, qb1, qb2);
        useSlot(s + 2, qc0, qc1, qc2);
        if (s + 6 < NFC) L(s + 6, qc0, qc1, qc2);
        useSlot(s + 3, qd0, qd1, qd2);
        if (s + 7 < NFC) L(s + 7, qd0, qd1, qd2);
    }
    useSlot(36, qa0, qa1, qa2);          // remainder 36,37,38
    useSlot(37, qb0, qb1, qb2);
    useSlot(38, qc0, qc1, qc2);

    // boundary for the tail wave: x_{2496}
    tp0[(size_t)NFC * cs] = make_float4(x[0], x[1], x[2], 0.0f);
}

__global__ __launch_bounds__(64)
void sde_replay(const float* __restrict__ A,
                const float* __restrict__ bv,
                const float* __restrict__ C,
                const float* __restrict__ dv,
                const float* __restrict__ noise,
                const float* __restrict__ trans,
                float* __restrict__ out)
{
    __shared__ float tile[96][66];   // rolling 32-state window: row = (j&31)*3+comp

    const int lane = threadIdx.x & 63;
    const int pg   = blockIdx.x & 63;              // path group
    const int c    = (NCH - 1) - (blockIdx.x >> 6); // REVERSED: 39(tail)..0
    const int b    = (pg << 6) | lane;
    const int phi  = (11 * lane) & 15;             // own path's alignment phase

    const float dt  = 0.002f;
    const float sdt = sqrtf(dt);

    float Adt[3][3], Cs[3][3], bdt[3], dsv[3];
#pragma unroll
    for (int i = 0; i < 3; ++i) {
        bdt[i] = bv[i] * dt;
        dsv[i] = dv[i] * sdt;
#pragma unroll
        for (int j = 0; j < 3; ++j) {
            Adt[i][j] = A[i * 3 + j] * dt;
            Cs[i][j]  = C[i * 3 + j] * sdt;
        }
    }

    const f4v xb = __builtin_nontemporal_load(
        (const f4v*)(trans + ((size_t)c * B_N + b) * 12));
    float x0r = xb.x, x1r = xb.y, x2r = xb.z;

    const float* __restrict__ nb0 = noise + (size_t)b * 3;
    const size_t nstride = (size_t)B_N * 3;
    const int base = c * CL;

    auto stepf = [&](float e0, float e1, float e2) {
        const float a0 = fmaf(Adt[0][2], x2r, fmaf(Adt[0][1], x1r, fmaf(Adt[0][0], x0r, bdt[0])));
        const float a1 = fmaf(Adt[1][2], x2r, fmaf(Adt[1][1], x1r, fmaf(Adt[1][0], x0r, bdt[1])));
        const float a2 = fmaf(Adt[2][2], x2r, fmaf(Adt[2][1], x1r, fmaf(Adt[2][0], x0r, bdt[2])));

        const float c0 = fmaf(Cs[0][2], x2r, fmaf(Cs[0][1], x1r, fmaf(Cs[0][0], x0r, dsv[0])));
        const float c1 = fmaf(Cs[1][2], x2r, fmaf(Cs[1][1], x1r, fmaf(Cs[1][0], x0r, dsv[1])));
        const float c2 = fmaf(Cs[2][2], x2r, fmaf(Cs[2][1], x1r, fmaf(Cs[2][0], x0r, dsv[2])));

        x0r = fmaf(c0, e0, x0r + a0);
        x1r = fmaf(c1, e1, x1r + a1);
        x2r = fmaf(c2, e2, x2r + a2);
    };

    if (c == NFC) {
        // tail wave: path p writes states [2496+phi, 2501) (only phi<=4 has any)
        float* op = out + (size_t)b * ROWF;
        if (phi == 0) {
            op[2496 * 3 + 0] = x0r; op[2496 * 3 + 1] = x1r; op[2496 * 3 + 2] = x2r;
        }
#pragma unroll
        for (int k = 0; k < 4; ++k) {
            const float* p = nb0 + (size_t)(2496 + k) * nstride;
            stepf(p[0], p[1], p[2]);
            const int j = k + 1;
            if (j >= phi) {
                float* d = op + (size_t)(2496 + j) * 3;
                d[0] = x0r; d[1] = x1r; d[2] = x2r;
            }
        }
        return;
    }

    const bool c0   = (c == 0);
    const bool last = (c == NFC - 1);

    // LDS helpers -----------------------------------------------------------
    auto tileWrite = [&](int j) {   // j compile-time in all uses
        const int r = (j & 31) * 3;
        tile[r + 0][lane] = x0r;
        tile[r + 1][lane] = x1r;
        tile[r + 2][lane] = x2r;
    };

    auto rawGuard = [&]() {   // tile writes visible before cross-lane reads
        asm volatile("s_waitcnt lgkmcnt(0)" ::: "memory");
        __builtin_amdgcn_sched_barrier(0);
    };
    auto warGuard = [&]() {   // prior flush's ds_reads done before row reuse
        asm volatile("s_waitcnt lgkmcnt(0)" ::: "memory");
        __builtin_amdgcn_sched_barrier(0);
    };

    // store roles: quad-group h=lane>>4 serves paths P=4i+h; m=lane&15 is the
    // triple index within the 192 B (16-state) aligned segment.
    const int h   = lane >> 4;
    const int m   = lane & 15;
    const int phh = (11 * h) & 15;
    float* const outG = out + (size_t)(pg << 6) * ROWF + (size_t)base * 3;

    auto flush = [&](auto fc, bool maskTail) {
        constexpr int F = decltype(fc)::value;
        rawGuard();
#pragma unroll
        for (int i = 0; i < 16; ++i) {
            const int P    = 4 * i + h;
            const int phiP = (12 * i + phh) & 15;   // (11*(4i+h)) & 15
            const int j    = phiP + 16 * F + m;     // local state index
            const int r    = (j & 31) * 3;
            const float v0 = tile[r + 0][P];
            const float v1 = tile[r + 1][P];
            const float v2 = tile[r + 2][P];
            if (!maskTail || (phiP + m) <= 20) {    // t = 2432+j <= 2500
                float* d = outG + (size_t)P * ROWF + (size_t)j * 3;
                __builtin_nontemporal_store(v0, d + 0);
                __builtin_nontemporal_store(v1, d + 1);
                __builtin_nontemporal_store(v2, d + 2);
            }
        }
    };

    // noise loads (clamped for c=38 overrun; garbage states are store-masked)
    float bufA[16][3], bufB[16][3];
    auto loadN = [&](float (&buf)[16][3], int kbase, auto cnt) {
        constexpr int CNT = decltype(cnt)::value;
#pragma unroll
        for (int k = 0; k < CNT; ++k) {
            int g = base + kbase + k;
            g = g > (T_N - 1) ? (T_N - 1) : g;
            const float* p = nb0 + (size_t)g * nstride;
            buf[k][0] = p[0];
            buf[k][1] = p[1];
            buf[k][2] = p[2];
        }
    };

    loadN(bufA, 0,  ic<16>{});   // eps k=0..15
    loadN(bufB, 16, ic<16>{});   // eps k=16..31

    // boundary state j=0 (row 0); head states for c==0
    tileWrite(0);
    if (c0 && phi > 0) {
        float* d = outG + (size_t)lane * ROWF;   // own path, t=0
        d[0] = x0r; d[1] = x1r; d[2] = x2r;
    }

    // P1: k=0..15 -> states 1..16
#pragma unroll
    for (int k = 0; k < 16; ++k) {
        stepf(bufA[k][0], bufA[k][1], bufA[k][2]);
        tileWrite(k + 1);
        if (c0 && (k + 1) < phi) {
            float* d = outG + (size_t)lane * ROWF + (size_t)(k + 1) * 3;
            d[0] = x0r; d[1] = x1r; d[2] = x2r;
        }
    }
    loadN(bufA, 32, ic<16>{});   // eps k=32..47

    // P2: k=16..30 -> states 17..31
#pragma unroll
    for (int k = 0; k < 15; ++k) {
        stepf(bufB[k][0], bufB[k][1], bufB[k][2]);
        tileWrite(k + 17);
    }

    flush(ic<0>{}, false);       // segments [phi, phi+16)

    // P3: k=31 (bufB[15]) -> state 32 ; then k=32..46 (bufA[0..14]) -> 33..47
    warGuard();
    stepf(bufB[15][0], bufB[15][1], bufB[15][2]);
    tileWrite(32);
    loadN(bufB, 48, ic<16>{});   // eps k=48..63 (bufB fully free now)
#pragma unroll
    for (int k = 0; k < 15; ++k) {
        stepf(bufA[k][0], bufA[k][1], bufA[k][2]);
        tileWrite(33 + k);
    }

    flush(ic<1>{}, false);       // segments [phi+16, phi+32)

    // P4: k=47 (bufA[15]) -> state 48 ; then k=48..62 (bufB[0..14]) -> 49..63
    warGuard();
    stepf(bufA[15][0], bufA[15][1], bufA[15][2]);
    tileWrite(48);
    loadN(bufA, 64, ic<15>{});   // eps k=64..78 (bufA[15] dead after this point)
#pragma unroll
    for (int k = 0; k < 15; ++k) {
        stepf(bufB[k][0], bufB[k][1], bufB[k][2]);
        tileWrite(49 + k);
    }

    flush(ic<2>{}, false);       // segments [phi+32, phi+48)

    // P5: k=63 (bufB[15]) -> state 64 ; then k=64..78 (bufA[0..14]) -> 65..79
    warGuard();
    stepf(bufB[15][0], bufB[15][1], bufB[15][2]);
    tileWrite(64);
#pragma unroll
    for (int k = 0; k < 15; ++k) {
        stepf(bufA[k][0], bufA[k][1], bufA[k][2]);
        tileWrite(65 + k);
    }

    flush(ic<3>{}, last);        // segments [phi+48, phi+64), masked at t>2500
}

extern "C" void kernel_launch(void* const* d_in, const int* in_sizes, int n_in,
                              void* d_out, int out_size, void* d_ws, size_t ws_size,
                              hipStream_t stream) {
    const float* x0    = (const float*)d_in[0];
    const float* A     = (const float*)d_in[1];
    const float* bv    = (const float*)d_in[2];
    const float* C     = (const float*)d_in[3];
    const float* dv    = (const float*)d_in[4];
    const float* noise = (const float*)d_in[5];
    float* out = (float*)d_out;

    float* trans = (float*)d_ws;   // 7.86 MB

    dim3 gridPC(B_N / 64, NFC);

    sde_chunk_transforms<<<gridPC, 64, 0, stream>>>(A, bv, C, dv, noise, trans);
    sde_scan<<<B_N / 64, 64, 0, stream>>>(x0, trans);
    sde_replay<<<64 * NCH, 64, 0, stream>>>(A, bv, C, dv, noise, trans, out);
}